// Round 6
// baseline (329.303 us; speedup 1.0000x reference)
//
#include <hip/hip_runtime.h>
#include <hip/hip_bf16.h>

#define N_NODES 100000
#define N_EDGES 1600000
#define D 128
#define NBUCKETS 391          // ceil(N_NODES/256), bucket = 256 rows
#define SORT_CAP 5120         // max entries/bucket (mean 4096, sigma 64)
#define NBLK_H 1563           // bhist: 1024 edges/block
#define BUCKET_EDGES 2048     // k_bucket edges/block
#define NBLK_B 782            // ceil(N_EDGES/2048)

typedef float  floatx4 __attribute__((ext_vector_type(4)));
typedef __bf16 bf16x8  __attribute__((ext_vector_type(8)));

__device__ __forceinline__ unsigned rotl32(unsigned x, int d) {
    return (x << d) | (x >> (32 - d));
}

// JAX threefry2x32 with key (0, 42)
__device__ __forceinline__ void threefry_0_42(unsigned c0, unsigned c1,
                                              unsigned& o0, unsigned& o1) {
    const unsigned k0 = 0u, k1 = 42u;
    const unsigned k2 = 0x1BD11BDAu ^ k0 ^ k1;
    unsigned x0 = c0 + k0;
    unsigned x1 = c1 + k1;
#define TF_R4(r0, r1, r2, r3)                      \
    x0 += x1; x1 = rotl32(x1, r0); x1 ^= x0;       \
    x0 += x1; x1 = rotl32(x1, r1); x1 ^= x0;       \
    x0 += x1; x1 = rotl32(x1, r2); x1 ^= x0;       \
    x0 += x1; x1 = rotl32(x1, r3); x1 ^= x0;
    TF_R4(13, 15, 26, 6);  x0 += k1; x1 += k2 + 1u;
    TF_R4(17, 29, 16, 24); x0 += k2; x1 += k0 + 2u;
    TF_R4(13, 15, 26, 6);  x0 += k0; x1 += k1 + 3u;
    TF_R4(17, 29, 16, 24); x0 += k1; x1 += k2 + 4u;
    TF_R4(13, 15, 26, 6);  x0 += k2; x1 += k0 + 5u;
#undef TF_R4
    o0 = x0; o1 = x1;
}

// Partitionable threefry (modern JAX default): element i -> counter (0, i),
// bits = o0 ^ o1; keep iff MSB(bits)==0.
__device__ __forceinline__ bool keep_elem(unsigned i) {
    unsigned o0, o1;
    threefry_0_42(0u, i, o0, o1);
    return (((o0 ^ o1) >> 31) == 0u);
}

__device__ __forceinline__ unsigned short f32_bf16(float f) {
    unsigned u = __float_as_uint(f);
    u += 0x7fffu + ((u >> 16) & 1u);   // RNE
    return (unsigned short)(u >> 16);
}

// ---------------- Phase 1: fused dropout + GEMM (bf16 MFMA) ----------------
__global__ __launch_bounds__(256)
void k_gemm(const float* __restrict__ x, const float* __restrict__ W,
            unsigned short* __restrict__ hb) {
    __shared__ __align__(16) unsigned short Wt[128][136];  // Wt[n][k] = bf16(W[k][n])
    __shared__ __align__(16) unsigned short xs[32][136];

    const int t = threadIdx.x;
    const int g = blockIdx.x;

    // stage W transposed -> bf16 (float4 loads: 16 iters instead of 64)
    for (int i4 = t; i4 < 128 * 32; i4 += 256) {
        float4 wv = ((const float4*)W)[i4];
        int k = i4 >> 5, n4 = (i4 & 31) * 4;
        Wt[n4 + 0][k] = f32_bf16(wv.x);
        Wt[n4 + 1][k] = f32_bf16(wv.y);
        Wt[n4 + 2][k] = f32_bf16(wv.z);
        Wt[n4 + 3][k] = f32_bf16(wv.w);
    }

    {
        int m  = t >> 4;
        int c0 = (t & 15) * 8;
        int r0 = g * 32 + m;
        const float* pa = x + r0 * D + c0;
        const float* pb = x + (r0 + 16) * D + c0;
        float va[8], vb[8];
        *(float4*)&va[0] = ((const float4*)pa)[0];
        *(float4*)&va[4] = ((const float4*)pa)[1];
        *(float4*)&vb[0] = ((const float4*)pb)[0];
        *(float4*)&vb[4] = ((const float4*)pb)[1];
        int ibase = r0 * D + c0;
#pragma unroll
        for (int j = 0; j < 8; ++j) {
            float fa = keep_elem((unsigned)(ibase + j))        ? 2.0f * va[j] : 0.0f;
            float fb = keep_elem((unsigned)(ibase + 2048 + j)) ? 2.0f * vb[j] : 0.0f;
            xs[m][c0 + j]      = f32_bf16(fa);
            xs[16 + m][c0 + j] = f32_bf16(fb);
        }
    }
    __syncthreads();

    const int w  = t >> 6;
    const int l  = t & 63;
    const int rt = w >> 1;
    const int ctbase = (w & 1) * 4;
    const int mm = l & 15;
    const int q  = l >> 4;
    const int koff = q * 8;
    const unsigned short* xrow = &xs[rt * 16 + mm][0];
    const int growbase = g * 32 + rt * 16;

    for (int ci = 0; ci < 4; ++ci) {
        int ct = ctbase + ci;
        const unsigned short* wrow = &Wt[ct * 16 + mm][0];
        floatx4 acc = {0.f, 0.f, 0.f, 0.f};
#pragma unroll
        for (int kt = 0; kt < 4; ++kt) {
            bf16x8 a = *(const bf16x8*)(xrow + kt * 32 + koff);
            bf16x8 b = *(const bf16x8*)(wrow + kt * 32 + koff);
            acc = __builtin_amdgcn_mfma_f32_16x16x32_bf16(a, b, acc, 0, 0, 0);
        }
        int col = ct * 16 + mm;
#pragma unroll
        for (int reg = 0; reg < 4; ++reg) {
            int grow = growbase + q * 4 + reg;
            hb[grow * D + col] = f32_bf16(acc[reg]);
        }
    }
}

// ---------------- Phase 2: bucketed CSR build ----------------
// 2a: per-block LDS histogram, 1024 edges/block (6x grid of r4/r5)
__global__ __launch_bounds__(256)
void k_bhist(const int* __restrict__ row, int* __restrict__ bcnt) {
    __shared__ int h[NBUCKETS];
    const int t = threadIdx.x;
    for (int i = t; i < NBUCKETS; i += 256) h[i] = 0;
    __syncthreads();
    int e4 = (blockIdx.x * 256 + t) * 4;
    if (e4 < N_EDGES) {
        int4 r = *(const int4*)(row + e4);
        atomicAdd(&h[r.x >> 8], 1);
        atomicAdd(&h[r.y >> 8], 1);
        atomicAdd(&h[r.z >> 8], 1);
        atomicAdd(&h[r.w >> 8], 1);
    }
    __syncthreads();
    for (int i = t; i < NBUCKETS; i += 256)
        if (h[i]) atomicAdd(&bcnt[i], h[i]);
}

__global__ __launch_bounds__(512)
void k_bscan(const int* __restrict__ bcnt, int* __restrict__ bstart,
             int* __restrict__ bcur, int* __restrict__ offsets) {
    __shared__ int s[512];
    int t = threadIdx.x;
    int v = (t < NBUCKETS) ? bcnt[t] : 0;
    s[t] = v;
    __syncthreads();
    for (int off = 1; off < 512; off <<= 1) {
        int a = (t >= off) ? s[t - off] : 0;
        __syncthreads();
        s[t] += a;
        __syncthreads();
    }
    if (t < NBUCKETS) {
        int st = s[t] - v;
        bstart[t] = st;
        bcur[t]   = st;
    }
    if (t == 0) {
        bstart[NBUCKETS]  = N_EDGES;
        offsets[N_NODES]  = N_EDGES;
    }
}

// 2c: bucket scatter, 2048 edges/block (2x grid of r4/r5)
// entry.x = col | (rowlow << 17), entry.y = float bits of val
__global__ __launch_bounds__(256)
void k_bucket(const int* __restrict__ row, const int* __restrict__ col,
              const float* __restrict__ val, int* __restrict__ bcur,
              int2* __restrict__ buf) {
    __shared__ int h[NBUCKETS];
    __shared__ int lbase[NBUCKETS];
    const int t = threadIdx.x;
    for (int i = t; i < NBUCKETS; i += 256) h[i] = 0;
    __syncthreads();

    int rows[8], cols[8];
    float vals[8];
    int base = blockIdx.x * BUCKET_EDGES;
#pragma unroll
    for (int k = 0; k < 2; ++k) {
        int e4 = base + (k * 256 + t) * 4;
        if (e4 < N_EDGES) {
            *(int4*)&rows[k * 4]   = *(const int4*)(row + e4);
            *(int4*)&cols[k * 4]   = *(const int4*)(col + e4);
            *(float4*)&vals[k * 4] = *(const float4*)(val + e4);
        } else {
            rows[k * 4] = rows[k * 4 + 1] = rows[k * 4 + 2] = rows[k * 4 + 3] = -1;
        }
    }
#pragma unroll
    for (int j = 0; j < 8; ++j)
        if (rows[j] >= 0) atomicAdd(&h[rows[j] >> 8], 1);
    __syncthreads();

    for (int i = t; i < NBUCKETS; i += 256) {
        int c = h[i];
        lbase[i] = c ? atomicAdd(&bcur[i], c) : 0;
    }
    __syncthreads();
    for (int i = t; i < NBUCKETS; i += 256) h[i] = 0;
    __syncthreads();

#pragma unroll
    for (int j = 0; j < 8; ++j) {
        if (rows[j] >= 0) {
            int b = rows[j] >> 8;
            int pos = lbase[b] + atomicAdd(&h[b], 1);
            int2 ent;
            ent.x = cols[j] | ((rows[j] & 255) << 17);
            ent.y = __float_as_int(vals[j]);
            buf[pos] = ent;
        }
    }
}

// 2d: per-bucket counting sort (LDS staging — r4 version), in-place
__global__ __launch_bounds__(256)
void k_sort(const int* __restrict__ bstart, int2* __restrict__ buf,
            int* __restrict__ offsets) {
    __shared__ int2 ents[SORT_CAP];
    __shared__ int s[256];
    __shared__ int cur[256];
    const int b = blockIdx.x, t = threadIdx.x;
    const int s0 = bstart[b];
    const int n  = bstart[b + 1] - s0;

    for (int i = t; i < n; i += 256) ents[i] = buf[s0 + i];
    s[t] = 0;
    __syncthreads();
    for (int i = t; i < n; i += 256) atomicAdd(&s[ents[i].x >> 17], 1);
    __syncthreads();
    int v = s[t];
    for (int off = 1; off < 256; off <<= 1) {
        int a = (t >= off) ? s[t - off] : 0;
        __syncthreads();
        s[t] += a;
        __syncthreads();
    }
    int excl = s[t] - v;
    int grow = (b << 8) + t;
    if (grow < N_NODES) offsets[grow] = s0 + excl;
    cur[t] = excl;
    __syncthreads();
    for (int i = t; i < n; i += 256) {
        int2 e = ents[i];
        int rl = e.x >> 17;
        int p  = s0 + atomicAdd(&cur[rl], 1);
        int2 o;
        o.x = e.x & 0x1FFFF;
        o.y = e.y;
        buf[p] = o;       // safe: source fully staged in LDS
    }
}

// ---------------- Phase 3: gather SpMM + ReLU (8x MLP — r4 version) --------
__global__ __launch_bounds__(256)
void k_gather(const unsigned short* __restrict__ hb,
              const int* __restrict__ offsets,
              const int2* __restrict__ csr, float* __restrict__ out) {
    int wid = blockIdx.x * 4 + (threadIdx.x >> 6);  // one wave per row
    int l2  = (threadIdx.x & 63) * 2;
    if (wid >= N_NODES) return;
    const unsigned short* hbl = hb + l2;
    int start = offsets[wid];
    int n     = offsets[wid + 1] - start;
    float a0 = 0.f, a1 = 0.f;
    int i = 0;
    for (; i + 8 <= n; i += 8) {
        int2 e[8];
#pragma unroll
        for (int j = 0; j < 8; ++j) e[j] = csr[start + i + j];
        unsigned hv[8];
#pragma unroll
        for (int j = 0; j < 8; ++j) hv[j] = *(const unsigned*)(hbl + e[j].x * D);
#pragma unroll
        for (int j = 0; j < 8; ++j) {
            float v = __int_as_float(e[j].y);
            a0 = fmaf(v, __uint_as_float(hv[j] << 16), a0);
            a1 = fmaf(v, __uint_as_float(hv[j] & 0xffff0000u), a1);
        }
    }
    for (; i + 4 <= n; i += 4) {
        int2 e[4];
#pragma unroll
        for (int j = 0; j < 4; ++j) e[j] = csr[start + i + j];
        unsigned hv[4];
#pragma unroll
        for (int j = 0; j < 4; ++j) hv[j] = *(const unsigned*)(hbl + e[j].x * D);
#pragma unroll
        for (int j = 0; j < 4; ++j) {
            float v = __int_as_float(e[j].y);
            a0 = fmaf(v, __uint_as_float(hv[j] << 16), a0);
            a1 = fmaf(v, __uint_as_float(hv[j] & 0xffff0000u), a1);
        }
    }
    for (; i < n; ++i) {
        int2 e = csr[start + i];
        float v = __int_as_float(e.y);
        unsigned hv = *(const unsigned*)(hbl + e.x * D);
        a0 = fmaf(v, __uint_as_float(hv << 16), a0);
        a1 = fmaf(v, __uint_as_float(hv & 0xffff0000u), a1);
    }
    float2 r;
    r.x = a0 > 0.f ? a0 : 0.f;
    r.y = a1 > 0.f ? a1 : 0.f;
    *(float2*)(out + wid * D + l2) = r;
}

extern "C" void kernel_launch(void* const* d_in, const int* in_sizes, int n_in,
                              void* d_out, int out_size, void* d_ws, size_t ws_size,
                              hipStream_t stream) {
    const float* x    = (const float*)d_in[0];
    const float* W    = (const float*)d_in[1];
    const int*   arow = (const int*)d_in[2];
    const int*   acol = (const int*)d_in[3];
    const float* aval = (const float*)d_in[4];
    float* out = (float*)d_out;

    char* ws = (char*)d_ws;
    unsigned short* hb = (unsigned short*)ws;            // 25,600,000 B
    size_t off = 25600000;
    int* offsets = (int*)(ws + off); off += 400016;      // N_NODES+1 ints
    int* bcnt    = (int*)(ws + off); off += 1568;        // NBUCKETS+1
    int* bstart  = (int*)(ws + off); off += 1568;
    int* bcur    = (int*)(ws + off); off += 1568;
    int2* buf    = (int2*)(ws + off); off += 12800000;   // packed edges -> final CSR
    // total ~38.8 MB

    hipMemsetAsync(bcnt, 0, 1568, stream);
    k_bhist <<<NBLK_H, 256, 0, stream>>>(arow, bcnt);
    k_bscan <<<1, 512, 0, stream>>>(bcnt, bstart, bcur, offsets);
    k_bucket<<<NBLK_B, 256, 0, stream>>>(arow, acol, aval, bcur, buf);
    k_sort  <<<NBUCKETS, 256, 0, stream>>>(bstart, buf, offsets);
    k_gemm  <<<3125, 256, 0, stream>>>(x, W, hb);
    k_gather<<<(N_NODES + 3) / 4, 256, 0, stream>>>(hb, offsets, buf, out);
}

// Round 7
// 257.948 us; speedup vs baseline: 1.2766x; 1.2766x over previous
//
#include <hip/hip_runtime.h>
#include <hip/hip_bf16.h>

#define N_NODES 100000
#define N_EDGES 1600000
#define D 128
#define NBUCKETS 391          // ceil(N_NODES/256), bucket = 256 rows
#define BUCKET_EDGES 4096     // edges per k_bhist/k_bucket block
#define NBLK1 391             // ceil(N_EDGES/BUCKET_EDGES)
#define SORT_CAP 5120         // max entries/bucket (mean 4096, sigma 64)

typedef float          floatx4 __attribute__((ext_vector_type(4)));
typedef __bf16         bf16x8  __attribute__((ext_vector_type(8)));
typedef unsigned short ushort8 __attribute__((ext_vector_type(8)));

__device__ __forceinline__ unsigned rotl32(unsigned x, int d) {
    return (x << d) | (x >> (32 - d));
}

// JAX threefry2x32 with key (0, 42)
__device__ __forceinline__ void threefry_0_42(unsigned c0, unsigned c1,
                                              unsigned& o0, unsigned& o1) {
    const unsigned k0 = 0u, k1 = 42u;
    const unsigned k2 = 0x1BD11BDAu ^ k0 ^ k1;
    unsigned x0 = c0 + k0;
    unsigned x1 = c1 + k1;
#define TF_R4(r0, r1, r2, r3)                      \
    x0 += x1; x1 = rotl32(x1, r0); x1 ^= x0;       \
    x0 += x1; x1 = rotl32(x1, r1); x1 ^= x0;       \
    x0 += x1; x1 = rotl32(x1, r2); x1 ^= x0;       \
    x0 += x1; x1 = rotl32(x1, r3); x1 ^= x0;
    TF_R4(13, 15, 26, 6);  x0 += k1; x1 += k2 + 1u;
    TF_R4(17, 29, 16, 24); x0 += k2; x1 += k0 + 2u;
    TF_R4(13, 15, 26, 6);  x0 += k0; x1 += k1 + 3u;
    TF_R4(17, 29, 16, 24); x0 += k1; x1 += k2 + 4u;
    TF_R4(13, 15, 26, 6);  x0 += k2; x1 += k0 + 5u;
#undef TF_R4
    o0 = x0; o1 = x1;
}

// Partitionable threefry (modern JAX default): element i -> counter (0, i),
// bits = o0 ^ o1; keep iff MSB(bits)==0.
__device__ __forceinline__ bool keep_elem(unsigned i) {
    unsigned o0, o1;
    threefry_0_42(0u, i, o0, o1);
    return (((o0 ^ o1) >> 31) == 0u);
}

__device__ __forceinline__ unsigned short f32_bf16(float f) {
    unsigned u = __float_as_uint(f);
    u += 0x7fffu + ((u >> 16) & 1u);   // RNE
    return (unsigned short)(u >> 16);
}

// ---------------- Phase 1: fused dropout + GEMM (bf16 MFMA) ----------------
// LDS staging uses ONLY b128 writes: at 68-dword row stride every bank gets
// exactly 8 of the wave's 256 dword-accesses -> zero excess conflicts.
__global__ __launch_bounds__(256)
void k_gemm(const float* __restrict__ x, const float* __restrict__ W,
            unsigned short* __restrict__ hb) {
    __shared__ __align__(16) unsigned short Wt[128][136];  // Wt[n][k] = bf16(W[k][n])
    __shared__ __align__(16) unsigned short xs[32][136];

    const int t = threadIdx.x;
    const int g = blockIdx.x;

    // stage W transposed: thread -> (col n, k-octet); global reads lane-coalesced
    // (lanes span consecutive n at fixed k), LDS write = one b128 per octet.
    {
        int n      = t & 127;
        int k8base = t >> 7;          // 0 or 1
#pragma unroll
        for (int it = 0; it < 8; ++it) {
            int k8 = (it * 2 + k8base) * 8;      // {0,8,...,120}
            unsigned short tmp[8];
#pragma unroll
            for (int j = 0; j < 8; ++j)
                tmp[j] = f32_bf16(W[(k8 + j) * 128 + n]);
            *(ushort8*)&Wt[n][k8] = *(ushort8*)tmp;
        }
    }

    // stage 32 x-rows with dropout; pack 8 bf16 -> one b128 write per row-octet
    {
        int m  = t >> 4;
        int c0 = (t & 15) * 8;
        int r0 = g * 32 + m;
        const float* pa = x + r0 * D + c0;
        const float* pb = x + (r0 + 16) * D + c0;
        float va[8], vb[8];
        *(float4*)&va[0] = ((const float4*)pa)[0];
        *(float4*)&va[4] = ((const float4*)pa)[1];
        *(float4*)&vb[0] = ((const float4*)pb)[0];
        *(float4*)&vb[4] = ((const float4*)pb)[1];
        int ibase = r0 * D + c0;
        unsigned short ta[8], tb[8];
#pragma unroll
        for (int j = 0; j < 8; ++j) {
            float fa = keep_elem((unsigned)(ibase + j))        ? 2.0f * va[j] : 0.0f;
            float fb = keep_elem((unsigned)(ibase + 2048 + j)) ? 2.0f * vb[j] : 0.0f;
            ta[j] = f32_bf16(fa);
            tb[j] = f32_bf16(fb);
        }
        *(ushort8*)&xs[m][c0]      = *(ushort8*)ta;
        *(ushort8*)&xs[16 + m][c0] = *(ushort8*)tb;
    }
    __syncthreads();

    const int w  = t >> 6;
    const int l  = t & 63;
    const int rt = w >> 1;
    const int ctbase = (w & 1) * 4;
    const int mm = l & 15;
    const int q  = l >> 4;
    const int koff = q * 8;
    const unsigned short* xrow = &xs[rt * 16 + mm][0];
    const int growbase = g * 32 + rt * 16;

    for (int ci = 0; ci < 4; ++ci) {
        int ct = ctbase + ci;
        const unsigned short* wrow = &Wt[ct * 16 + mm][0];
        floatx4 acc = {0.f, 0.f, 0.f, 0.f};
#pragma unroll
        for (int kt = 0; kt < 4; ++kt) {
            bf16x8 a = *(const bf16x8*)(xrow + kt * 32 + koff);
            bf16x8 b = *(const bf16x8*)(wrow + kt * 32 + koff);
            acc = __builtin_amdgcn_mfma_f32_16x16x32_bf16(a, b, acc, 0, 0, 0);
        }
        int col = ct * 16 + mm;
#pragma unroll
        for (int reg = 0; reg < 4; ++reg) {
            int grow = growbase + q * 4 + reg;
            hb[grow * D + col] = f32_bf16(acc[reg]);
        }
    }
}

// ---------------- Phase 2: bucketed CSR build (r4 forms) ----------------
__global__ __launch_bounds__(256)
void k_bhist(const int* __restrict__ row, int* __restrict__ bcnt) {
    __shared__ int h[NBUCKETS];
    const int t = threadIdx.x;
    for (int i = t; i < NBUCKETS; i += 256) h[i] = 0;
    __syncthreads();
    int base = blockIdx.x * BUCKET_EDGES;
#pragma unroll
    for (int k = 0; k < 4; ++k) {
        int e4 = base + (k * 256 + t) * 4;
        if (e4 < N_EDGES) {
            int4 r = *(const int4*)(row + e4);
            atomicAdd(&h[r.x >> 8], 1);
            atomicAdd(&h[r.y >> 8], 1);
            atomicAdd(&h[r.z >> 8], 1);
            atomicAdd(&h[r.w >> 8], 1);
        }
    }
    __syncthreads();
    for (int i = t; i < NBUCKETS; i += 256)
        if (h[i]) atomicAdd(&bcnt[i], h[i]);
}

__global__ __launch_bounds__(512)
void k_bscan(const int* __restrict__ bcnt, int* __restrict__ bstart,
             int* __restrict__ bcur, int* __restrict__ offsets) {
    __shared__ int s[512];
    int t = threadIdx.x;
    int v = (t < NBUCKETS) ? bcnt[t] : 0;
    s[t] = v;
    __syncthreads();
    for (int off = 1; off < 512; off <<= 1) {
        int a = (t >= off) ? s[t - off] : 0;
        __syncthreads();
        s[t] += a;
        __syncthreads();
    }
    if (t < NBUCKETS) {
        int st = s[t] - v;
        bstart[t] = st;
        bcur[t]   = st;
    }
    if (t == 0) {
        bstart[NBUCKETS]  = N_EDGES;
        offsets[N_NODES]  = N_EDGES;
    }
}

// entry.x = col | (rowlow << 17), entry.y = float bits of val
__global__ __launch_bounds__(256)
void k_bucket(const int* __restrict__ row, const int* __restrict__ col,
              const float* __restrict__ val, int* __restrict__ bcur,
              int2* __restrict__ buf) {
    __shared__ int h[NBUCKETS];
    __shared__ int lbase[NBUCKETS];
    const int t = threadIdx.x;
    for (int i = t; i < NBUCKETS; i += 256) h[i] = 0;
    __syncthreads();

    int rows[16], cols[16];
    float vals[16];
    int base = blockIdx.x * BUCKET_EDGES;
#pragma unroll
    for (int k = 0; k < 4; ++k) {
        int e4 = base + (k * 256 + t) * 4;
        if (e4 < N_EDGES) {
            *(int4*)&rows[k * 4]   = *(const int4*)(row + e4);
            *(int4*)&cols[k * 4]   = *(const int4*)(col + e4);
            *(float4*)&vals[k * 4] = *(const float4*)(val + e4);
        } else {
            rows[k * 4] = rows[k * 4 + 1] = rows[k * 4 + 2] = rows[k * 4 + 3] = -1;
        }
    }
#pragma unroll
    for (int j = 0; j < 16; ++j)
        if (rows[j] >= 0) atomicAdd(&h[rows[j] >> 8], 1);
    __syncthreads();

    for (int i = t; i < NBUCKETS; i += 256) {
        int c = h[i];
        lbase[i] = c ? atomicAdd(&bcur[i], c) : 0;
    }
    __syncthreads();
    for (int i = t; i < NBUCKETS; i += 256) h[i] = 0;
    __syncthreads();

#pragma unroll
    for (int j = 0; j < 16; ++j) {
        if (rows[j] >= 0) {
            int b = rows[j] >> 8;
            int pos = lbase[b] + atomicAdd(&h[b], 1);
            int2 ent;
            ent.x = cols[j] | ((rows[j] & 255) << 17);
            ent.y = __float_as_int(vals[j]);
            buf[pos] = ent;
        }
    }
}

// 2d: per-bucket counting sort (LDS staging), in-place
__global__ __launch_bounds__(256)
void k_sort(const int* __restrict__ bstart, int2* __restrict__ buf,
            int* __restrict__ offsets) {
    __shared__ int2 ents[SORT_CAP];
    __shared__ int s[256];
    __shared__ int cur[256];
    const int b = blockIdx.x, t = threadIdx.x;
    const int s0 = bstart[b];
    const int n  = bstart[b + 1] - s0;

    for (int i = t; i < n; i += 256) ents[i] = buf[s0 + i];
    s[t] = 0;
    __syncthreads();
    for (int i = t; i < n; i += 256) atomicAdd(&s[ents[i].x >> 17], 1);
    __syncthreads();
    int v = s[t];
    for (int off = 1; off < 256; off <<= 1) {
        int a = (t >= off) ? s[t - off] : 0;
        __syncthreads();
        s[t] += a;
        __syncthreads();
    }
    int excl = s[t] - v;
    int grow = (b << 8) + t;
    if (grow < N_NODES) offsets[grow] = s0 + excl;
    cur[t] = excl;
    __syncthreads();
    for (int i = t; i < n; i += 256) {
        int2 e = ents[i];
        int rl = e.x >> 17;
        int p  = s0 + atomicAdd(&cur[rl], 1);
        int2 o;
        o.x = e.x & 0x1FFFF;
        o.y = e.y;
        buf[p] = o;       // safe: source fully staged in LDS
    }
}

// ---------------- Phase 3: gather SpMM + ReLU (8x MLP) ----------------
__global__ __launch_bounds__(256)
void k_gather(const unsigned short* __restrict__ hb,
              const int* __restrict__ offsets,
              const int2* __restrict__ csr, float* __restrict__ out) {
    int wid = blockIdx.x * 4 + (threadIdx.x >> 6);  // one wave per row
    int l2  = (threadIdx.x & 63) * 2;
    if (wid >= N_NODES) return;
    const unsigned short* hbl = hb + l2;
    int start = offsets[wid];
    int n     = offsets[wid + 1] - start;
    float a0 = 0.f, a1 = 0.f;
    int i = 0;
    for (; i + 8 <= n; i += 8) {
        int2 e[8];
#pragma unroll
        for (int j = 0; j < 8; ++j) e[j] = csr[start + i + j];
        unsigned hv[8];
#pragma unroll
        for (int j = 0; j < 8; ++j) hv[j] = *(const unsigned*)(hbl + e[j].x * D);
#pragma unroll
        for (int j = 0; j < 8; ++j) {
            float v = __int_as_float(e[j].y);
            a0 = fmaf(v, __uint_as_float(hv[j] << 16), a0);
            a1 = fmaf(v, __uint_as_float(hv[j] & 0xffff0000u), a1);
        }
    }
    for (; i + 4 <= n; i += 4) {
        int2 e[4];
#pragma unroll
        for (int j = 0; j < 4; ++j) e[j] = csr[start + i + j];
        unsigned hv[4];
#pragma unroll
        for (int j = 0; j < 4; ++j) hv[j] = *(const unsigned*)(hbl + e[j].x * D);
#pragma unroll
        for (int j = 0; j < 4; ++j) {
            float v = __int_as_float(e[j].y);
            a0 = fmaf(v, __uint_as_float(hv[j] << 16), a0);
            a1 = fmaf(v, __uint_as_float(hv[j] & 0xffff0000u), a1);
        }
    }
    for (; i < n; ++i) {
        int2 e = csr[start + i];
        float v = __int_as_float(e.y);
        unsigned hv = *(const unsigned*)(hbl + e.x * D);
        a0 = fmaf(v, __uint_as_float(hv << 16), a0);
        a1 = fmaf(v, __uint_as_float(hv & 0xffff0000u), a1);
    }
    float2 r;
    r.x = a0 > 0.f ? a0 : 0.f;
    r.y = a1 > 0.f ? a1 : 0.f;
    *(float2*)(out + wid * D + l2) = r;
}

extern "C" void kernel_launch(void* const* d_in, const int* in_sizes, int n_in,
                              void* d_out, int out_size, void* d_ws, size_t ws_size,
                              hipStream_t stream) {
    const float* x    = (const float*)d_in[0];
    const float* W    = (const float*)d_in[1];
    const int*   arow = (const int*)d_in[2];
    const int*   acol = (const int*)d_in[3];
    const float* aval = (const float*)d_in[4];
    float* out = (float*)d_out;

    char* ws = (char*)d_ws;
    unsigned short* hb = (unsigned short*)ws;            // 25,600,000 B
    size_t off = 25600000;
    int* offsets = (int*)(ws + off); off += 400016;      // N_NODES+1 ints
    int* bcnt    = (int*)(ws + off); off += 1568;        // NBUCKETS+1
    int* bstart  = (int*)(ws + off); off += 1568;
    int* bcur    = (int*)(ws + off); off += 1568;
    int2* buf    = (int2*)(ws + off); off += 12800000;   // packed edges -> final CSR
    // total ~38.8 MB

    hipMemsetAsync(bcnt, 0, 1568, stream);
    k_bhist <<<NBLK1, 256, 0, stream>>>(arow, bcnt);
    k_bscan <<<1, 512, 0, stream>>>(bcnt, bstart, bcur, offsets);
    k_bucket<<<NBLK1, 256, 0, stream>>>(arow, acol, aval, bcur, buf);
    k_sort  <<<NBUCKETS, 256, 0, stream>>>(bstart, buf, offsets);
    k_gemm  <<<3125, 256, 0, stream>>>(x, W, hb);
    k_gather<<<(N_NODES + 3) / 4, 256, 0, stream>>>(hb, offsets, buf, out);
}

// Round 8
// 255.430 us; speedup vs baseline: 1.2892x; 1.0099x over previous
//
#include <hip/hip_runtime.h>
#include <hip/hip_bf16.h>

#define N_NODES 100000
#define N_EDGES 1600000
#define D 128
#define NBUCKETS 391          // ceil(N_NODES/256), bucket = 256 rows
#define BUCKET_EDGES 4096     // edges per bhist/bucket phase block
#define NBLK1 391             // ceil(N_EDGES/BUCKET_EDGES)
#define SORT_CAP 5120         // max entries/bucket (mean 4096, sigma 64)
#define GEMM_TILES 3125

typedef float          floatx4 __attribute__((ext_vector_type(4)));
typedef __bf16         bf16x8  __attribute__((ext_vector_type(8)));
typedef unsigned short ushort8 __attribute__((ext_vector_type(8)));

// Shared-memory union: gemm path and CSR phases never coexist in one block.
union __align__(16) Smem {
    struct { unsigned short Wt[128][136]; unsigned short xs[32][136]; } g; // 43520 B
    struct { int h[NBUCKETS]; } bh;
    struct { int s[512]; } bs;
    struct { int h[NBUCKETS]; int lbase[NBUCKETS]; } bk;
    struct { int2 ents[SORT_CAP]; int s[256]; int cur[256]; } st;          // 42968 B
};

__device__ __forceinline__ unsigned rotl32(unsigned x, int d) {
    return (x << d) | (x >> (32 - d));
}

// JAX threefry2x32 with key (0, 42)
__device__ __forceinline__ void threefry_0_42(unsigned c0, unsigned c1,
                                              unsigned& o0, unsigned& o1) {
    const unsigned k0 = 0u, k1 = 42u;
    const unsigned k2 = 0x1BD11BDAu ^ k0 ^ k1;
    unsigned x0 = c0 + k0;
    unsigned x1 = c1 + k1;
#define TF_R4(r0, r1, r2, r3)                      \
    x0 += x1; x1 = rotl32(x1, r0); x1 ^= x0;       \
    x0 += x1; x1 = rotl32(x1, r1); x1 ^= x0;       \
    x0 += x1; x1 = rotl32(x1, r2); x1 ^= x0;       \
    x0 += x1; x1 = rotl32(x1, r3); x1 ^= x0;
    TF_R4(13, 15, 26, 6);  x0 += k1; x1 += k2 + 1u;
    TF_R4(17, 29, 16, 24); x0 += k2; x1 += k0 + 2u;
    TF_R4(13, 15, 26, 6);  x0 += k0; x1 += k1 + 3u;
    TF_R4(17, 29, 16, 24); x0 += k1; x1 += k2 + 4u;
    TF_R4(13, 15, 26, 6);  x0 += k2; x1 += k0 + 5u;
#undef TF_R4
    o0 = x0; o1 = x1;
}

// Partitionable threefry (modern JAX default): element i -> counter (0, i),
// bits = o0 ^ o1; keep iff MSB(bits)==0.
__device__ __forceinline__ bool keep_elem(unsigned i) {
    unsigned o0, o1;
    threefry_0_42(0u, i, o0, o1);
    return (((o0 ^ o1) >> 31) == 0u);
}

__device__ __forceinline__ unsigned short f32_bf16(float f) {
    unsigned u = __float_as_uint(f);
    u += 0x7fffu + ((u >> 16) & 1u);   // RNE
    return (unsigned short)(u >> 16);
}

// ---------------- fused dropout + GEMM tile (bf16 MFMA) ----------------
// All-b128 LDS staging: zero excess bank conflicts (r7-verified).
__device__ __forceinline__ void gemm_tile(int g, int t,
        const float* __restrict__ x, const float* __restrict__ W,
        unsigned short* __restrict__ hb, Smem& u) {
    {
        int n      = t & 127;
        int k8base = t >> 7;
#pragma unroll
        for (int it = 0; it < 8; ++it) {
            int k8 = (it * 2 + k8base) * 8;
            unsigned short tmp[8];
#pragma unroll
            for (int j = 0; j < 8; ++j)
                tmp[j] = f32_bf16(W[(k8 + j) * 128 + n]);
            *(ushort8*)&u.g.Wt[n][k8] = *(ushort8*)tmp;
        }
    }
    {
        int m  = t >> 4;
        int c0 = (t & 15) * 8;
        int r0 = g * 32 + m;
        const float* pa = x + r0 * D + c0;
        const float* pb = x + (r0 + 16) * D + c0;
        float va[8], vb[8];
        *(float4*)&va[0] = ((const float4*)pa)[0];
        *(float4*)&va[4] = ((const float4*)pa)[1];
        *(float4*)&vb[0] = ((const float4*)pb)[0];
        *(float4*)&vb[4] = ((const float4*)pb)[1];
        int ibase = r0 * D + c0;
        unsigned short ta[8], tb[8];
#pragma unroll
        for (int j = 0; j < 8; ++j) {
            float fa = keep_elem((unsigned)(ibase + j))        ? 2.0f * va[j] : 0.0f;
            float fb = keep_elem((unsigned)(ibase + 2048 + j)) ? 2.0f * vb[j] : 0.0f;
            ta[j] = f32_bf16(fa);
            tb[j] = f32_bf16(fb);
        }
        *(ushort8*)&u.g.xs[m][c0]      = *(ushort8*)ta;
        *(ushort8*)&u.g.xs[16 + m][c0] = *(ushort8*)tb;
    }
    __syncthreads();

    const int w  = t >> 6;
    const int l  = t & 63;
    const int rt = w >> 1;
    const int ctbase = (w & 1) * 4;
    const int mm = l & 15;
    const int q  = l >> 4;
    const int koff = q * 8;
    const unsigned short* xrow = &u.g.xs[rt * 16 + mm][0];
    const int growbase = g * 32 + rt * 16;

    for (int ci = 0; ci < 4; ++ci) {
        int ct = ctbase + ci;
        const unsigned short* wrow = &u.g.Wt[ct * 16 + mm][0];
        floatx4 acc = {0.f, 0.f, 0.f, 0.f};
#pragma unroll
        for (int kt = 0; kt < 4; ++kt) {
            bf16x8 a = *(const bf16x8*)(xrow + kt * 32 + koff);
            bf16x8 b = *(const bf16x8*)(wrow + kt * 32 + koff);
            acc = __builtin_amdgcn_mfma_f32_16x16x32_bf16(a, b, acc, 0, 0, 0);
        }
        int col = ct * 16 + mm;
#pragma unroll
        for (int reg = 0; reg < 4; ++reg) {
            int grow = growbase + q * 4 + reg;
            hb[grow * D + col] = f32_bf16(acc[reg]);
        }
    }
}

// ---------------- L1: bhist phase + gemm quarter ----------------
__global__ __launch_bounds__(256)
void k_l1(const int* __restrict__ row, int* __restrict__ bcnt,
          const float* __restrict__ x, const float* __restrict__ W,
          unsigned short* __restrict__ hb, int gemmBase) {
    __shared__ Smem u;
    const int b = blockIdx.x, t = threadIdx.x;
    if (b >= NBLK1) { gemm_tile(gemmBase + b - NBLK1, t, x, W, hb, u); return; }

    for (int i = t; i < NBUCKETS; i += 256) u.bh.h[i] = 0;
    __syncthreads();
    int base = b * BUCKET_EDGES;
#pragma unroll
    for (int k = 0; k < 4; ++k) {
        int e4 = base + (k * 256 + t) * 4;
        if (e4 < N_EDGES) {
            int4 r = *(const int4*)(row + e4);
            atomicAdd(&u.bh.h[r.x >> 8], 1);
            atomicAdd(&u.bh.h[r.y >> 8], 1);
            atomicAdd(&u.bh.h[r.z >> 8], 1);
            atomicAdd(&u.bh.h[r.w >> 8], 1);
        }
    }
    __syncthreads();
    for (int i = t; i < NBUCKETS; i += 256)
        if (u.bh.h[i]) atomicAdd(&bcnt[i], u.bh.h[i]);
}

// ---------------- L2: bscan phase (256-thread, 512-elem scan) + gemm -------
__global__ __launch_bounds__(256)
void k_l2(const int* __restrict__ bcnt, int* __restrict__ bstart,
          int* __restrict__ bcur, int* __restrict__ offsets,
          const float* __restrict__ x, const float* __restrict__ W,
          unsigned short* __restrict__ hb, int gemmBase) {
    __shared__ Smem u;
    const int b = blockIdx.x, t = threadIdx.x;
    if (b >= 1) { gemm_tile(gemmBase + b - 1, t, x, W, hb, u); return; }

    int i0 = t, i1 = t + 256;
    int v0 = (i0 < NBUCKETS) ? bcnt[i0] : 0;
    int v1 = (i1 < NBUCKETS) ? bcnt[i1] : 0;
    u.bs.s[i0] = v0;
    u.bs.s[i1] = v1;
    __syncthreads();
    for (int off = 1; off < 512; off <<= 1) {
        int a0 = (i0 >= off) ? u.bs.s[i0 - off] : 0;
        int a1 = (i1 >= off) ? u.bs.s[i1 - off] : 0;
        __syncthreads();
        u.bs.s[i0] += a0;
        u.bs.s[i1] += a1;
        __syncthreads();
    }
    if (i0 < NBUCKETS) { int st = u.bs.s[i0] - v0; bstart[i0] = st; bcur[i0] = st; }
    if (i1 < NBUCKETS) { int st = u.bs.s[i1] - v1; bstart[i1] = st; bcur[i1] = st; }
    if (t == 0) {
        bstart[NBUCKETS] = N_EDGES;
        offsets[N_NODES] = N_EDGES;
    }
}

// ---------------- L3: bucket phase + gemm quarter ----------------
// entry.x = col | (rowlow << 17), entry.y = float bits of val
__global__ __launch_bounds__(256)
void k_l3(const int* __restrict__ row, const int* __restrict__ col,
          const float* __restrict__ val, int* __restrict__ bcur,
          int2* __restrict__ buf,
          const float* __restrict__ x, const float* __restrict__ W,
          unsigned short* __restrict__ hb, int gemmBase) {
    __shared__ Smem u;
    const int b = blockIdx.x, t = threadIdx.x;
    if (b >= NBLK1) { gemm_tile(gemmBase + b - NBLK1, t, x, W, hb, u); return; }

    for (int i = t; i < NBUCKETS; i += 256) u.bk.h[i] = 0;
    __syncthreads();

    int rows[16], cols[16];
    float vals[16];
    int base = b * BUCKET_EDGES;
#pragma unroll
    for (int k = 0; k < 4; ++k) {
        int e4 = base + (k * 256 + t) * 4;
        if (e4 < N_EDGES) {
            *(int4*)&rows[k * 4]   = *(const int4*)(row + e4);
            *(int4*)&cols[k * 4]   = *(const int4*)(col + e4);
            *(float4*)&vals[k * 4] = *(const float4*)(val + e4);
        } else {
            rows[k * 4] = rows[k * 4 + 1] = rows[k * 4 + 2] = rows[k * 4 + 3] = -1;
        }
    }
#pragma unroll
    for (int j = 0; j < 16; ++j)
        if (rows[j] >= 0) atomicAdd(&u.bk.h[rows[j] >> 8], 1);
    __syncthreads();

    for (int i = t; i < NBUCKETS; i += 256) {
        int c = u.bk.h[i];
        u.bk.lbase[i] = c ? atomicAdd(&bcur[i], c) : 0;
    }
    __syncthreads();
    for (int i = t; i < NBUCKETS; i += 256) u.bk.h[i] = 0;
    __syncthreads();

#pragma unroll
    for (int j = 0; j < 16; ++j) {
        if (rows[j] >= 0) {
            int bb = rows[j] >> 8;
            int pos = u.bk.lbase[bb] + atomicAdd(&u.bk.h[bb], 1);
            int2 ent;
            ent.x = cols[j] | ((rows[j] & 255) << 17);
            ent.y = __float_as_int(vals[j]);
            buf[pos] = ent;
        }
    }
}

// ---------------- L4: sort phase (per-bucket counting sort) + gemm ---------
__global__ __launch_bounds__(256)
void k_l4(const int* __restrict__ bstart, int2* __restrict__ buf,
          int* __restrict__ offsets,
          const float* __restrict__ x, const float* __restrict__ W,
          unsigned short* __restrict__ hb, int gemmBase) {
    __shared__ Smem u;
    const int b = blockIdx.x, t = threadIdx.x;
    if (b >= NBUCKETS) { gemm_tile(gemmBase + b - NBUCKETS, t, x, W, hb, u); return; }

    const int s0 = bstart[b];
    const int n  = bstart[b + 1] - s0;

    for (int i = t; i < n; i += 256) u.st.ents[i] = buf[s0 + i];
    u.st.s[t] = 0;
    __syncthreads();
    for (int i = t; i < n; i += 256) atomicAdd(&u.st.s[u.st.ents[i].x >> 17], 1);
    __syncthreads();
    int v = u.st.s[t];
    for (int off = 1; off < 256; off <<= 1) {
        int a = (t >= off) ? u.st.s[t - off] : 0;
        __syncthreads();
        u.st.s[t] += a;
        __syncthreads();
    }
    int excl = u.st.s[t] - v;
    int grow = (b << 8) + t;
    if (grow < N_NODES) offsets[grow] = s0 + excl;
    u.st.cur[t] = excl;
    __syncthreads();
    for (int i = t; i < n; i += 256) {
        int2 e = u.st.ents[i];
        int rl = e.x >> 17;
        int p  = s0 + atomicAdd(&u.st.cur[rl], 1);
        int2 o;
        o.x = e.x & 0x1FFFF;
        o.y = e.y;
        buf[p] = o;       // safe: source fully staged in LDS
    }
}

// ---------------- L5: gather SpMM + ReLU (8x MLP) ----------------
__global__ __launch_bounds__(256)
void k_gather(const unsigned short* __restrict__ hb,
              const int* __restrict__ offsets,
              const int2* __restrict__ csr, float* __restrict__ out) {
    int wid = blockIdx.x * 4 + (threadIdx.x >> 6);  // one wave per row
    int l2  = (threadIdx.x & 63) * 2;
    if (wid >= N_NODES) return;
    const unsigned short* hbl = hb + l2;
    int start = offsets[wid];
    int n     = offsets[wid + 1] - start;
    float a0 = 0.f, a1 = 0.f;
    int i = 0;
    for (; i + 8 <= n; i += 8) {
        int2 e[8];
#pragma unroll
        for (int j = 0; j < 8; ++j) e[j] = csr[start + i + j];
        unsigned hv[8];
#pragma unroll
        for (int j = 0; j < 8; ++j) hv[j] = *(const unsigned*)(hbl + e[j].x * D);
#pragma unroll
        for (int j = 0; j < 8; ++j) {
            float v = __int_as_float(e[j].y);
            a0 = fmaf(v, __uint_as_float(hv[j] << 16), a0);
            a1 = fmaf(v, __uint_as_float(hv[j] & 0xffff0000u), a1);
        }
    }
    for (; i + 4 <= n; i += 4) {
        int2 e[4];
#pragma unroll
        for (int j = 0; j < 4; ++j) e[j] = csr[start + i + j];
        unsigned hv[4];
#pragma unroll
        for (int j = 0; j < 4; ++j) hv[j] = *(const unsigned*)(hbl + e[j].x * D);
#pragma unroll
        for (int j = 0; j < 4; ++j) {
            float v = __int_as_float(e[j].y);
            a0 = fmaf(v, __uint_as_float(hv[j] << 16), a0);
            a1 = fmaf(v, __uint_as_float(hv[j] & 0xffff0000u), a1);
        }
    }
    for (; i < n; ++i) {
        int2 e = csr[start + i];
        float v = __int_as_float(e.y);
        unsigned hv = *(const unsigned*)(hbl + e.x * D);
        a0 = fmaf(v, __uint_as_float(hv << 16), a0);
        a1 = fmaf(v, __uint_as_float(hv & 0xffff0000u), a1);
    }
    float2 r;
    r.x = a0 > 0.f ? a0 : 0.f;
    r.y = a1 > 0.f ? a1 : 0.f;
    *(float2*)(out + wid * D + l2) = r;
}

extern "C" void kernel_launch(void* const* d_in, const int* in_sizes, int n_in,
                              void* d_out, int out_size, void* d_ws, size_t ws_size,
                              hipStream_t stream) {
    const float* x    = (const float*)d_in[0];
    const float* W    = (const float*)d_in[1];
    const int*   arow = (const int*)d_in[2];
    const int*   acol = (const int*)d_in[3];
    const float* aval = (const float*)d_in[4];
    float* out = (float*)d_out;

    char* ws = (char*)d_ws;
    unsigned short* hb = (unsigned short*)ws;            // 25,600,000 B
    size_t off = 25600000;
    int* offsets = (int*)(ws + off); off += 400016;      // N_NODES+1 ints
    int* bcnt    = (int*)(ws + off); off += 1568;        // NBUCKETS+1
    int* bstart  = (int*)(ws + off); off += 1568;
    int* bcur    = (int*)(ws + off); off += 1568;
    int2* buf    = (int2*)(ws + off); off += 12800000;   // packed edges -> final CSR
    // total ~38.8 MB

    // gemm tile quarters riding on each CSR launch: 782+781+781+781 = 3125
    hipMemsetAsync(bcnt, 0, 1568, stream);
    k_l1<<<NBLK1 + 782, 256, 0, stream>>>(arow, bcnt, x, W, hb, 0);
    k_l2<<<1 + 781,     256, 0, stream>>>(bcnt, bstart, bcur, offsets, x, W, hb, 782);
    k_l3<<<NBLK1 + 781, 256, 0, stream>>>(arow, acol, aval, bcur, buf, x, W, hb, 1563);
    k_l4<<<NBUCKETS + 781, 256, 0, stream>>>(bstart, buf, offsets, x, W, hb, 2344);
    k_gather<<<(N_NODES + 3) / 4, 256, 0, stream>>>(hb, offsets, buf, out);
}

// Round 9
// 241.614 us; speedup vs baseline: 1.3629x; 1.0572x over previous
//
#include <hip/hip_runtime.h>
#include <hip/hip_bf16.h>

#define N_NODES 100000
#define N_EDGES 1600000
#define D 128
#define NBUCKETS 391          // ceil(N_NODES/256), bucket = 256 rows
#define BUCKET_EDGES 4096     // edges per bhist/bucket block
#define NBLK1 391             // ceil(N_EDGES/BUCKET_EDGES)
#define HCAP 2432             // half-bucket entry cap (mean 2048, sigma 45, +8.5s)

typedef float          floatx4 __attribute__((ext_vector_type(4)));
typedef __bf16         bf16x8  __attribute__((ext_vector_type(8)));
typedef unsigned short ushort8 __attribute__((ext_vector_type(8)));

__device__ __forceinline__ unsigned rotl32(unsigned x, int d) {
    return (x << d) | (x >> (32 - d));
}

// JAX threefry2x32 with key (0, 42)
__device__ __forceinline__ void threefry_0_42(unsigned c0, unsigned c1,
                                              unsigned& o0, unsigned& o1) {
    const unsigned k0 = 0u, k1 = 42u;
    const unsigned k2 = 0x1BD11BDAu ^ k0 ^ k1;
    unsigned x0 = c0 + k0;
    unsigned x1 = c1 + k1;
#define TF_R4(r0, r1, r2, r3)                      \
    x0 += x1; x1 = rotl32(x1, r0); x1 ^= x0;       \
    x0 += x1; x1 = rotl32(x1, r1); x1 ^= x0;       \
    x0 += x1; x1 = rotl32(x1, r2); x1 ^= x0;       \
    x0 += x1; x1 = rotl32(x1, r3); x1 ^= x0;
    TF_R4(13, 15, 26, 6);  x0 += k1; x1 += k2 + 1u;
    TF_R4(17, 29, 16, 24); x0 += k2; x1 += k0 + 2u;
    TF_R4(13, 15, 26, 6);  x0 += k0; x1 += k1 + 3u;
    TF_R4(17, 29, 16, 24); x0 += k1; x1 += k2 + 4u;
    TF_R4(13, 15, 26, 6);  x0 += k2; x1 += k0 + 5u;
#undef TF_R4
    o0 = x0; o1 = x1;
}

// Partitionable threefry (modern JAX default): element i -> counter (0, i),
// bits = o0 ^ o1; keep iff MSB(bits)==0.
__device__ __forceinline__ bool keep_elem(unsigned i) {
    unsigned o0, o1;
    threefry_0_42(0u, i, o0, o1);
    return (((o0 ^ o1) >> 31) == 0u);
}

__device__ __forceinline__ unsigned short f32_bf16(float f) {
    unsigned u = __float_as_uint(f);
    u += 0x7fffu + ((u >> 16) & 1u);   // RNE
    return (unsigned short)(u >> 16);
}

// ---------------- Phase 1: fused dropout + GEMM (bf16 MFMA) ----------------
// All-b128 LDS staging: zero excess bank conflicts (r7-verified).
__global__ __launch_bounds__(256)
void k_gemm(const float* __restrict__ x, const float* __restrict__ W,
            unsigned short* __restrict__ hb) {
    __shared__ __align__(16) unsigned short Wt[128][136];  // Wt[n][k] = bf16(W[k][n])
    __shared__ __align__(16) unsigned short xs[32][136];

    const int t = threadIdx.x;
    const int g = blockIdx.x;

    {
        int n      = t & 127;
        int k8base = t >> 7;
#pragma unroll
        for (int it = 0; it < 8; ++it) {
            int k8 = (it * 2 + k8base) * 8;
            unsigned short tmp[8];
#pragma unroll
            for (int j = 0; j < 8; ++j)
                tmp[j] = f32_bf16(W[(k8 + j) * 128 + n]);
            *(ushort8*)&Wt[n][k8] = *(ushort8*)tmp;
        }
    }
    {
        int m  = t >> 4;
        int c0 = (t & 15) * 8;
        int r0 = g * 32 + m;
        const float* pa = x + r0 * D + c0;
        const float* pb = x + (r0 + 16) * D + c0;
        float va[8], vb[8];
        *(float4*)&va[0] = ((const float4*)pa)[0];
        *(float4*)&va[4] = ((const float4*)pa)[1];
        *(float4*)&vb[0] = ((const float4*)pb)[0];
        *(float4*)&vb[4] = ((const float4*)pb)[1];
        int ibase = r0 * D + c0;
        unsigned short ta[8], tb[8];
#pragma unroll
        for (int j = 0; j < 8; ++j) {
            float fa = keep_elem((unsigned)(ibase + j))        ? 2.0f * va[j] : 0.0f;
            float fb = keep_elem((unsigned)(ibase + 2048 + j)) ? 2.0f * vb[j] : 0.0f;
            ta[j] = f32_bf16(fa);
            tb[j] = f32_bf16(fb);
        }
        *(ushort8*)&xs[m][c0]      = *(ushort8*)ta;
        *(ushort8*)&xs[16 + m][c0] = *(ushort8*)tb;
    }
    __syncthreads();

    const int w  = t >> 6;
    const int l  = t & 63;
    const int rt = w >> 1;
    const int ctbase = (w & 1) * 4;
    const int mm = l & 15;
    const int q  = l >> 4;
    const int koff = q * 8;
    const unsigned short* xrow = &xs[rt * 16 + mm][0];
    const int growbase = g * 32 + rt * 16;

    for (int ci = 0; ci < 4; ++ci) {
        int ct = ctbase + ci;
        const unsigned short* wrow = &Wt[ct * 16 + mm][0];
        floatx4 acc = {0.f, 0.f, 0.f, 0.f};
#pragma unroll
        for (int kt = 0; kt < 4; ++kt) {
            bf16x8 a = *(const bf16x8*)(xrow + kt * 32 + koff);
            bf16x8 b = *(const bf16x8*)(wrow + kt * 32 + koff);
            acc = __builtin_amdgcn_mfma_f32_16x16x32_bf16(a, b, acc, 0, 0, 0);
        }
        int col = ct * 16 + mm;
#pragma unroll
        for (int reg = 0; reg < 4; ++reg) {
            int grow = growbase + q * 4 + reg;
            hb[grow * D + col] = f32_bf16(acc[reg]);
        }
    }
}

// ---------------- Phase 2: bucketed staging ----------------
__global__ __launch_bounds__(256)
void k_bhist(const int* __restrict__ row, int* __restrict__ bcnt) {
    __shared__ int h[NBUCKETS];
    const int t = threadIdx.x;
    for (int i = t; i < NBUCKETS; i += 256) h[i] = 0;
    __syncthreads();
    int base = blockIdx.x * BUCKET_EDGES;
#pragma unroll
    for (int k = 0; k < 4; ++k) {
        int e4 = base + (k * 256 + t) * 4;
        if (e4 < N_EDGES) {
            int4 r = *(const int4*)(row + e4);
            atomicAdd(&h[r.x >> 8], 1);
            atomicAdd(&h[r.y >> 8], 1);
            atomicAdd(&h[r.z >> 8], 1);
            atomicAdd(&h[r.w >> 8], 1);
        }
    }
    __syncthreads();
    for (int i = t; i < NBUCKETS; i += 256)
        if (h[i]) atomicAdd(&bcnt[i], h[i]);
}

__global__ __launch_bounds__(512)
void k_bscan(const int* __restrict__ bcnt, int* __restrict__ bstart,
             int* __restrict__ bcur) {
    __shared__ int s[512];
    int t = threadIdx.x;
    int v = (t < NBUCKETS) ? bcnt[t] : 0;
    s[t] = v;
    __syncthreads();
    for (int off = 1; off < 512; off <<= 1) {
        int a = (t >= off) ? s[t - off] : 0;
        __syncthreads();
        s[t] += a;
        __syncthreads();
    }
    if (t < NBUCKETS) {
        int st = s[t] - v;
        bstart[t] = st;
        bcur[t]   = st;
    }
    if (t == 0) bstart[NBUCKETS] = N_EDGES;
}

// entry.x = col | (rowlow << 17), entry.y = float bits of val
__global__ __launch_bounds__(256)
void k_bucket(const int* __restrict__ row, const int* __restrict__ col,
              const float* __restrict__ val, int* __restrict__ bcur,
              int2* __restrict__ buf) {
    __shared__ int h[NBUCKETS];
    __shared__ int lbase[NBUCKETS];
    const int t = threadIdx.x;
    for (int i = t; i < NBUCKETS; i += 256) h[i] = 0;
    __syncthreads();

    int rows[16], cols[16];
    float vals[16];
    int base = blockIdx.x * BUCKET_EDGES;
#pragma unroll
    for (int k = 0; k < 4; ++k) {
        int e4 = base + (k * 256 + t) * 4;
        if (e4 < N_EDGES) {
            *(int4*)&rows[k * 4]   = *(const int4*)(row + e4);
            *(int4*)&cols[k * 4]   = *(const int4*)(col + e4);
            *(float4*)&vals[k * 4] = *(const float4*)(val + e4);
        } else {
            rows[k * 4] = rows[k * 4 + 1] = rows[k * 4 + 2] = rows[k * 4 + 3] = -1;
        }
    }
#pragma unroll
    for (int j = 0; j < 16; ++j)
        if (rows[j] >= 0) atomicAdd(&h[rows[j] >> 8], 1);
    __syncthreads();

    for (int i = t; i < NBUCKETS; i += 256) {
        int c = h[i];
        lbase[i] = c ? atomicAdd(&bcur[i], c) : 0;
    }
    __syncthreads();
    for (int i = t; i < NBUCKETS; i += 256) h[i] = 0;
    __syncthreads();

#pragma unroll
    for (int j = 0; j < 16; ++j) {
        if (rows[j] >= 0) {
            int bb = rows[j] >> 8;
            int pos = lbase[bb] + atomicAdd(&h[bb], 1);
            int2 ent;
            ent.x = cols[j] | ((rows[j] & 255) << 17);
            ent.y = __float_as_int(vals[j]);
            buf[pos] = ent;
        }
    }
}

// ---------------- Phase 3: fused sort + gather + ReLU ----------------
// Block b handles half-bucket: bucket = b>>1, rows [half*128, half*128+128).
// Sorts its half's entries in LDS, gathers h, writes out directly.
__global__ __launch_bounds__(512)
void k_sortgather(const int* __restrict__ bstart, const int2* __restrict__ buf,
                  const unsigned short* __restrict__ hb, float* __restrict__ out) {
    __shared__ __align__(16) int2 ents[HCAP];
    __shared__ __align__(16) int2 ents2[HCAP];
    __shared__ int cnt_[128];
    __shared__ int scan_[128];
    __shared__ int cur_[128];
    __shared__ int nkeep;

    const int b = blockIdx.x, t = threadIdx.x;
    const int bucket = b >> 1;
    const int rbase  = (b & 1) << 7;      // 0 or 128
    const int s0 = bstart[bucket];
    const int n  = bstart[bucket + 1] - s0;

    if (t < 128) cnt_[t] = 0;
    if (t == 0)  nkeep = 0;
    __syncthreads();

    // stage: keep entries whose rowlow is in our half; histogram on the fly
    for (int i = t; i < n; i += 512) {
        int2 e = buf[s0 + i];
        int rl = (e.x >> 17) - rbase;
        if ((unsigned)rl < 128u) {
            int p = atomicAdd(&nkeep, 1);
            ents[p] = e;
            atomicAdd(&cnt_[rl], 1);
        }
    }
    __syncthreads();

    // inclusive scan over 128 rowlow counters
    if (t < 128) scan_[t] = cnt_[t];
    __syncthreads();
    for (int off = 1; off < 128; off <<= 1) {
        int a = 0;
        if (t < 128 && t >= off) a = scan_[t - off];
        __syncthreads();
        if (t < 128) scan_[t] += a;
        __syncthreads();
    }
    if (t < 128) cur_[t] = scan_[t] - cnt_[t];   // exclusive start
    __syncthreads();

    // counting-sort scatter (LDS -> LDS)
    int nk = nkeep;
    for (int p = t; p < nk; p += 512) {
        int2 e = ents[p];
        int rl = (e.x >> 17) - rbase;
        int pos = atomicAdd(&cur_[rl], 1);
        ents2[pos] = e;
    }
    __syncthreads();

    // gather: wave w -> rowlows [16w, 16w+16); lane -> cols l2, l2+1
    const int w  = t >> 6;
    const int l2 = (t & 63) * 2;
    const unsigned short* hbl = hb + l2;
    for (int r = 0; r < 16; ++r) {
        int rl = w * 16 + r;
        int c  = cnt_[rl];
        int b0 = scan_[rl] - c;
        float a0 = 0.f, a1 = 0.f;
        int i = 0;
        for (; i + 8 <= c; i += 8) {
            int2 e[8];
#pragma unroll
            for (int j = 0; j < 8; ++j) e[j] = ents2[b0 + i + j];
            unsigned hv[8];
#pragma unroll
            for (int j = 0; j < 8; ++j)
                hv[j] = *(const unsigned*)(hbl + (e[j].x & 0x1FFFF) * D);
#pragma unroll
            for (int j = 0; j < 8; ++j) {
                float v = __int_as_float(e[j].y);
                a0 = fmaf(v, __uint_as_float(hv[j] << 16), a0);
                a1 = fmaf(v, __uint_as_float(hv[j] & 0xffff0000u), a1);
            }
        }
        for (; i + 4 <= c; i += 4) {
            int2 e[4];
#pragma unroll
            for (int j = 0; j < 4; ++j) e[j] = ents2[b0 + i + j];
            unsigned hv[4];
#pragma unroll
            for (int j = 0; j < 4; ++j)
                hv[j] = *(const unsigned*)(hbl + (e[j].x & 0x1FFFF) * D);
#pragma unroll
            for (int j = 0; j < 4; ++j) {
                float v = __int_as_float(e[j].y);
                a0 = fmaf(v, __uint_as_float(hv[j] << 16), a0);
                a1 = fmaf(v, __uint_as_float(hv[j] & 0xffff0000u), a1);
            }
        }
        for (; i < c; ++i) {
            int2 e = ents2[b0 + i];
            float v = __int_as_float(e.y);
            unsigned hv = *(const unsigned*)(hbl + (e.x & 0x1FFFF) * D);
            a0 = fmaf(v, __uint_as_float(hv << 16), a0);
            a1 = fmaf(v, __uint_as_float(hv & 0xffff0000u), a1);
        }
        int grow = (bucket << 8) + rbase + rl;
        if (grow < N_NODES) {
            float2 rr;
            rr.x = a0 > 0.f ? a0 : 0.f;
            rr.y = a1 > 0.f ? a1 : 0.f;
            *(float2*)(out + grow * D + l2) = rr;
        }
    }
}

extern "C" void kernel_launch(void* const* d_in, const int* in_sizes, int n_in,
                              void* d_out, int out_size, void* d_ws, size_t ws_size,
                              hipStream_t stream) {
    const float* x    = (const float*)d_in[0];
    const float* W    = (const float*)d_in[1];
    const int*   arow = (const int*)d_in[2];
    const int*   acol = (const int*)d_in[3];
    const float* aval = (const float*)d_in[4];
    float* out = (float*)d_out;

    char* ws = (char*)d_ws;
    unsigned short* hb = (unsigned short*)ws;            // 25,600,000 B
    size_t off = 25600000;
    int* bcnt   = (int*)(ws + off); off += 1568;         // NBUCKETS+1
    int* bstart = (int*)(ws + off); off += 1568;
    int* bcur   = (int*)(ws + off); off += 1568;
    int2* buf   = (int2*)(ws + off); off += 12800000;    // bucketed edges
    // total ~38.4 MB

    hipMemsetAsync(bcnt, 0, 1568, stream);
    k_bhist      <<<NBLK1, 256, 0, stream>>>(arow, bcnt);
    k_bscan      <<<1, 512, 0, stream>>>(bcnt, bstart, bcur);
    k_bucket     <<<NBLK1, 256, 0, stream>>>(arow, acol, aval, bcur, buf);
    k_gemm       <<<3125, 256, 0, stream>>>(x, W, hb);
    k_sortgather <<<2 * NBUCKETS, 512, 0, stream>>>(bstart, buf, hb, out);
}